// Round 10
// baseline (59.421 us; speedup 1.0000x reference)
//
#include <hip/hip_runtime.h>
#include <hip/hip_fp16.h>
#include <math.h>

// Problem constants (match reference)
#define PH 256
#define PW 512
#define NRAYS (PH * PW)     // 131072
#define NS 300
#define NB64 (NRAYS / 64)   // 2048 one-wave blocks
#define PI_F 3.14159265358979323846f

// Padded f16 volume: P[zp][yp][xp], zp in [0,66], yp/xp in [0,257].
// Logical (zz,y,x) = (zp-1, yp-1, xp-1); zz=0 -> ground 1000, zz in [1,64] ->
// voxel[zz-1], everything else (pads) = 0. Zero padding == reference's
// out-of-range gather = 0, so the render loop needs NO bounds logic at all.
// f16 footprint: 67*258*258*2 B = 8.9 MB (vs 17.8 MB f32) -> L2-resident.
#define XS 258
#define SS (258 * 258)          // 66564
#define ZSL 67
#define PVOX_ELEMS (ZSL * SS)   // 4,459,788
#define WS_VOL_OFF 32768

__device__ __forceinline__ float lerpf(float a, float b, float f) {
    return fmaf(f, b - a, a);
}

__global__ __launch_bounds__(256)
void pack_kernel(const float* __restrict__ vox, __half* __restrict__ pv) {
    const int idx = blockIdx.x * 256 + threadIdx.x;
    if (idx >= PVOX_ELEMS) return;
    const int zp = idx / SS;
    const int rem = idx - zp * SS;
    const int yp = rem / XS;
    const int xp = rem - yp * XS;
    const int x = xp - 1, y = yp - 1, zz = zp - 1;
    float v = 0.0f;
    if (((unsigned)x < 256u) & ((unsigned)y < 256u)) {
        if (zz == 0) v = 1000.0f;
        else if ((unsigned)(zz - 1) < 64u) v = vox[((zz - 1) << 16) + (y << 8) + x];
    }
    pv[idx] = __float2half_rn(v);
}

__device__ __forceinline__ float sample_sigma(const __half* __restrict__ pvv,
                                              float fs, float sxd, float syd, float szd) {
    const float xf = fmaf(fs, sxd, 127.5f);
    const float yf = fmaf(fs, syd, 127.5f);
    const float zf = fmaf(fs, szd, 1.53125f);
    const float xw = floorf(xf), yw = floorf(yf), zw = floorf(zf);
    const float fx = xf - xw, fy = yf - yw, fz = zf - zw;
    const int x0 = (int)xw, y0 = (int)yw, z0 = (int)zw;
    const int off = z0 * SS + y0 * XS + x0 + (SS + XS + 1);   // +1 pad shift each axis
    const __half* p = pvv + off;
    const float c000 = __half2float(p[0]);
    const float c001 = __half2float(p[1]);
    const float c010 = __half2float(p[XS]);
    const float c011 = __half2float(p[XS + 1]);
    const float c100 = __half2float(p[SS]);
    const float c101 = __half2float(p[SS + 1]);
    const float c110 = __half2float(p[SS + XS]);
    const float c111 = __half2float(p[SS + XS + 1]);
    const float l00 = lerpf(c000, c001, fx);
    const float l01 = lerpf(c010, c011, fx);
    const float l10 = lerpf(c100, c101, fx);
    const float l11 = lerpf(c110, c111, fx);
    return lerpf(lerpf(l00, l01, fy), lerpf(l10, l11, fy), fz);
}

__global__ __launch_bounds__(64)
void render_kernel(const __half* __restrict__ pvv,
                   float* __restrict__ out,
                   float* __restrict__ bmin, float* __restrict__ bmax) {
    const int lane = threadIdx.x;
    const int r = blockIdx.x * 64 + lane;
    const int h = r >> 9;
    const int w = r & (PW - 1);

    const float lat = (0.5f - (float)h * (1.0f / 255.0f)) * PI_F;
    const float lon = (-0.5f - 2.0f * (float)w * (1.0f / 511.0f)) * PI_F;
    float cl, sl, clon, slon;
    __sincosf(lat, &sl, &cl);
    __sincosf(lon, &slon, &clon);
    const float sxd = cl * clon * (128.0f / NS);
    const float syd = -cl * slon * (128.0f / NS);
    const float szd = sl * (65.0f / NS);
    const float intv = 64.0f / (float)NS;

    // Ray-box clip: samples with pos outside box have exactly sigma=0 (pads),
    // and the box is convex so once out, always out. Samples s=1..nrun valid.
    const float m = 1e-3f;
    float nx = 1e9f, ny = 1e9f, nz = 1e9f;
    if (sxd >  1e-8f) nx = (256.0f - m - 127.5f) / sxd;
    if (sxd < -1e-8f) nx = (127.5f - (-1.0f + m)) / (-sxd);
    if (syd >  1e-8f) ny = (256.0f - m - 127.5f) / syd;
    if (syd < -1e-8f) ny = (127.5f - (-1.0f + m)) / (-syd);
    if (szd >  1e-8f) nz = (65.0f - m - 1.53125f) / szd;
    if (szd < -1e-8f) nz = (1.53125f - (-1.0f + m)) / (-szd);
    const float nmin = fminf(fminf(nx, ny), nz);
    int nrun = NS;
    if (nmin < (float)NS) nrun = (int)nmin;
    if (nrun < 0) nrun = 0;

    float T = 1.0f, depth = 0.0f, opac = 0.0f, dval = 0.0f;

    int i = 0;
    for (; i + 4 <= nrun; i += 4) {
        float sg[4];
        const float fb = (float)i;
        #pragma unroll
        for (int j = 0; j < 4; ++j)
            sg[j] = sample_sigma(pvv, fb + (float)(j + 1), sxd, syd, szd);
        #pragma unroll
        for (int j = 0; j < 4; ++j) {
            const float e = __expf(-sg[j] * intv);
            const float prob = fmaf(-T, e, T);     // T*(1-e)
            dval += intv;
            depth = fmaf(prob, dval, depth);
            opac += prob;
            T *= e;
        }
        if (T < 1e-6f) break;
    }
    if (T >= 1e-6f) {
        for (; i < nrun; ++i) {
            const float sg = sample_sigma(pvv, (float)(i + 1), sxd, syd, szd);
            const float e = __expf(-sg * intv);
            const float prob = fmaf(-T, e, T);
            dval += intv;
            depth = fmaf(prob, dval, depth);
            opac += prob;
            T *= e;
            if (T < 1e-6f) break;
        }
    }

    out[r] = depth;
    out[NRAYS + r] = opac;

    // wave min/max of depth
    float mn = depth, mx = depth;
    #pragma unroll
    for (int off = 32; off > 0; off >>= 1) {
        mn = fminf(mn, __shfl_xor(mn, off));
        mx = fmaxf(mx, __shfl_xor(mx, off));
    }
    if (lane == 0) {
        bmin[blockIdx.x] = mn;
        bmax[blockIdx.x] = mx;
    }
}

__global__ __launch_bounds__(256)
void reduce_minmax_kernel(const float* __restrict__ blockMin,
                          const float* __restrict__ blockMax,
                          float* __restrict__ mm) {
    __shared__ float smn[256];
    __shared__ float smx[256];
    const int t = threadIdx.x;
    float mn = 1e30f, mx = -1e30f;
    for (int i = t; i < NB64; i += 256) {
        mn = fminf(mn, blockMin[i]);
        mx = fmaxf(mx, blockMax[i]);
    }
    smn[t] = mn;
    smx[t] = mx;
    __syncthreads();
    #pragma unroll
    for (int sft = 128; sft > 0; sft >>= 1) {
        if (t < sft) {
            smn[t] = fminf(smn[t], smn[t + sft]);
            smx[t] = fmaxf(smx[t], smx[t + sft]);
        }
        __syncthreads();
    }
    if (t == 0) {
        mm[0] = smn[0];
        mm[1] = smx[0];
    }
}

__global__ __launch_bounds__(256)
void normalize_kernel(float* __restrict__ out, const float* __restrict__ mm) {
    const int r = blockIdx.x * 256 + threadIdx.x;
    const float mn = mm[0];
    const float mx = mm[1];
    out[r] = (out[r] - mn) / (mx - mn);
}

extern "C" void kernel_launch(void* const* d_in, const int* in_sizes, int n_in,
                              void* d_out, int out_size, void* d_ws, size_t ws_size,
                              hipStream_t stream) {
    const float* vox = (const float*)d_in[0];
    float* out = (float*)d_out;
    char* ws = (char*)d_ws;
    float* bmin = (float*)ws;               // 2048 floats
    float* bmax = (float*)(ws + 8192);      // 2048 floats
    float* mm   = (float*)(ws + 16384);     // 2 floats
    __half* pv = (__half*)(ws + WS_VOL_OFF);

    const int pblocks = (PVOX_ELEMS + 255) / 256;
    pack_kernel<<<pblocks, 256, 0, stream>>>(vox, pv);
    render_kernel<<<NB64, 64, 0, stream>>>(pv, out, bmin, bmax);
    reduce_minmax_kernel<<<1, 256, 0, stream>>>(bmin, bmax, mm);
    normalize_kernel<<<NRAYS / 256, 256, 0, stream>>>(out, mm);
}

// Round 11
// 51.231 us; speedup vs baseline: 1.1599x; 1.1599x over previous
//
#include <hip/hip_runtime.h>
#include <math.h>

// Problem constants (match reference)
#define PH 256
#define PW 512
#define NRAYS (PH * PW)     // 131072
#define NS 300
#define NB64 (NRAYS / 64)   // 2048 one-wave blocks
#define PI_F 3.14159265358979323846f

// Padded f32 volume: P[zp][yp][xp], zp in [0,66], yp/xp in [0,257].
// Logical (zz,y,x) = (zp-1, yp-1, xp-1); zz=0 -> ground 1000, zz in [1,64] ->
// voxel[zz-1], everything else (pads) = 0. Zero padding == reference's
// out-of-range gather = 0, so the render loop needs NO bounds logic at all.
#define XS 258
#define SS (258 * 258)          // 66564
#define ZSL 67
#define PVOX_ELEMS (ZSL * SS)   // 4,459,788
#define WS_VOL_OFF 32768

__device__ __forceinline__ float lerpf(float a, float b, float f) {
    return fmaf(f, b - a, a);
}

__global__ __launch_bounds__(256)
void pack_kernel(const float* __restrict__ vox, float* __restrict__ pv) {
    const int idx = blockIdx.x * 256 + threadIdx.x;
    if (idx >= PVOX_ELEMS) return;
    const int zp = idx / SS;
    const int rem = idx - zp * SS;
    const int yp = rem / XS;
    const int xp = rem - yp * XS;
    const int x = xp - 1, y = yp - 1, zz = zp - 1;
    float v = 0.0f;
    if (((unsigned)x < 256u) & ((unsigned)y < 256u)) {
        if (zz == 0) v = 1000.0f;
        else if ((unsigned)(zz - 1) < 64u) v = vox[((zz - 1) << 16) + (y << 8) + x];
    }
    pv[idx] = v;
}

__device__ __forceinline__ float sample_sigma(const float* __restrict__ pvv,
                                              float fs, float sxd, float syd, float szd) {
    const float xf = fmaf(fs, sxd, 127.5f);
    const float yf = fmaf(fs, syd, 127.5f);
    const float zf = fmaf(fs, szd, 1.53125f);
    const float xw = floorf(xf), yw = floorf(yf), zw = floorf(zf);
    const float fx = xf - xw, fy = yf - yw, fz = zf - zw;
    const int x0 = (int)xw, y0 = (int)yw, z0 = (int)zw;
    const int off = z0 * SS + y0 * XS + x0 + (SS + XS + 1);   // +1 pad shift each axis
    const float* p = pvv + off;
    const float c000 = p[0];
    const float c001 = p[1];
    const float c010 = p[XS];
    const float c011 = p[XS + 1];
    const float c100 = p[SS];
    const float c101 = p[SS + 1];
    const float c110 = p[SS + XS];
    const float c111 = p[SS + XS + 1];
    const float l00 = lerpf(c000, c001, fx);
    const float l01 = lerpf(c010, c011, fx);
    const float l10 = lerpf(c100, c101, fx);
    const float l11 = lerpf(c110, c111, fx);
    return lerpf(lerpf(l00, l01, fy), lerpf(l10, l11, fy), fz);
}

// One wave = one 8x8 pixel tile: lanes' rays point in nearly-identical
// directions, so their trilinear stencils at step i overlap heavily ->
// L1-coherent gathers (vs the 45-degree azimuth arc of a 64x1 row strip).
__global__ __launch_bounds__(64)
void render_kernel(const float* __restrict__ pvv,
                   float* __restrict__ out,
                   float* __restrict__ bmin, float* __restrict__ bmax) {
    const int lane = threadIdx.x;
    const int b = blockIdx.x;
    const int h = ((b >> 6) << 3) + (lane >> 3);    // tileRow*8 + lane/8
    const int w = ((b & 63) << 3) + (lane & 7);     // tileCol*8 + lane%8
    const int r = (h << 9) + w;

    const float lat = (0.5f - (float)h * (1.0f / 255.0f)) * PI_F;
    const float lon = (-0.5f - 2.0f * (float)w * (1.0f / 511.0f)) * PI_F;
    float cl, sl, clon, slon;
    __sincosf(lat, &sl, &cl);
    __sincosf(lon, &slon, &clon);
    const float sxd = cl * clon * (128.0f / NS);
    const float syd = -cl * slon * (128.0f / NS);
    const float szd = sl * (65.0f / NS);
    const float intv = 64.0f / (float)NS;

    // Ray-box clip: samples with pos outside box have exactly sigma=0 (pads),
    // and the box is convex so once out, always out. Samples s=1..nrun valid.
    const float m = 1e-3f;
    float nx = 1e9f, ny = 1e9f, nz = 1e9f;
    if (sxd >  1e-8f) nx = (256.0f - m - 127.5f) / sxd;
    if (sxd < -1e-8f) nx = (127.5f - (-1.0f + m)) / (-sxd);
    if (syd >  1e-8f) ny = (256.0f - m - 127.5f) / syd;
    if (syd < -1e-8f) ny = (127.5f - (-1.0f + m)) / (-syd);
    if (szd >  1e-8f) nz = (65.0f - m - 1.53125f) / szd;
    if (szd < -1e-8f) nz = (1.53125f - (-1.0f + m)) / (-szd);
    const float nmin = fminf(fminf(nx, ny), nz);
    int nrun = NS;
    if (nmin < (float)NS) nrun = (int)nmin;
    if (nrun < 0) nrun = 0;

    float T = 1.0f, depth = 0.0f, opac = 0.0f, dval = 0.0f;

    int i = 0;
    for (; i + 4 <= nrun; i += 4) {
        float sg[4];
        const float fb = (float)i;
        #pragma unroll
        for (int j = 0; j < 4; ++j)
            sg[j] = sample_sigma(pvv, fb + (float)(j + 1), sxd, syd, szd);
        #pragma unroll
        for (int j = 0; j < 4; ++j) {
            const float e = __expf(-sg[j] * intv);
            const float prob = fmaf(-T, e, T);     // T*(1-e)
            dval += intv;
            depth = fmaf(prob, dval, depth);
            opac += prob;
            T *= e;
        }
        if (T < 1e-6f) break;
    }
    if (T >= 1e-6f) {
        for (; i < nrun; ++i) {
            const float sg = sample_sigma(pvv, (float)(i + 1), sxd, syd, szd);
            const float e = __expf(-sg * intv);
            const float prob = fmaf(-T, e, T);
            dval += intv;
            depth = fmaf(prob, dval, depth);
            opac += prob;
            T *= e;
            if (T < 1e-6f) break;
        }
    }

    out[r] = depth;
    out[NRAYS + r] = opac;

    // wave min/max of depth
    float mn = depth, mx = depth;
    #pragma unroll
    for (int off = 32; off > 0; off >>= 1) {
        mn = fminf(mn, __shfl_xor(mn, off));
        mx = fmaxf(mx, __shfl_xor(mx, off));
    }
    if (lane == 0) {
        bmin[blockIdx.x] = mn;
        bmax[blockIdx.x] = mx;
    }
}

__global__ __launch_bounds__(256)
void reduce_minmax_kernel(const float* __restrict__ blockMin,
                          const float* __restrict__ blockMax,
                          float* __restrict__ mm) {
    __shared__ float smn[256];
    __shared__ float smx[256];
    const int t = threadIdx.x;
    float mn = 1e30f, mx = -1e30f;
    for (int i = t; i < NB64; i += 256) {
        mn = fminf(mn, blockMin[i]);
        mx = fmaxf(mx, blockMax[i]);
    }
    smn[t] = mn;
    smx[t] = mx;
    __syncthreads();
    #pragma unroll
    for (int sft = 128; sft > 0; sft >>= 1) {
        if (t < sft) {
            smn[t] = fminf(smn[t], smn[t + sft]);
            smx[t] = fmaxf(smx[t], smx[t + sft]);
        }
        __syncthreads();
    }
    if (t == 0) {
        mm[0] = smn[0];
        mm[1] = smx[0];
    }
}

__global__ __launch_bounds__(256)
void normalize_kernel(float* __restrict__ out, const float* __restrict__ mm) {
    const int r = blockIdx.x * 256 + threadIdx.x;
    const float mn = mm[0];
    const float mx = mm[1];
    out[r] = (out[r] - mn) / (mx - mn);
}

extern "C" void kernel_launch(void* const* d_in, const int* in_sizes, int n_in,
                              void* d_out, int out_size, void* d_ws, size_t ws_size,
                              hipStream_t stream) {
    const float* vox = (const float*)d_in[0];
    float* out = (float*)d_out;
    char* ws = (char*)d_ws;
    float* bmin = (float*)ws;               // 2048 floats
    float* bmax = (float*)(ws + 8192);      // 2048 floats
    float* mm   = (float*)(ws + 16384);     // 2 floats
    float* pv = (float*)(ws + WS_VOL_OFF);

    const int pblocks = (PVOX_ELEMS + 255) / 256;
    pack_kernel<<<pblocks, 256, 0, stream>>>(vox, pv);
    render_kernel<<<NB64, 64, 0, stream>>>(pv, out, bmin, bmax);
    reduce_minmax_kernel<<<1, 256, 0, stream>>>(bmin, bmax, mm);
    normalize_kernel<<<NRAYS / 256, 256, 0, stream>>>(out, mm);
}

// Round 12
// 41.092 us; speedup vs baseline: 1.4460x; 1.2467x over previous
//
#include <hip/hip_runtime.h>
#include <math.h>

// Problem constants (match reference)
#define PH 256
#define PW 512
#define NRAYS (PH * PW)     // 131072
#define NS 300
#define NB64 (NRAYS / 64)   // 2048 one-wave blocks
#define PI_F 3.14159265358979323846f

// Padded f32 volume: P[zp][yp][xp], zp in [0,66], yp/xp in [0,257].
// Logical (zz,y,x) = (zp-1, yp-1, xp-1); zz=0 -> ground 1000, zz in [1,64] ->
// voxel[zz-1], everything else (pads) = 0. Zero padding == reference's
// out-of-range gather = 0, so the render loop needs NO bounds logic at all.
#define XS 258
#define SS (258 * 258)          // 66564
#define ZSL 67
#define PVOX_ELEMS (ZSL * SS)   // 4,459,788
#define WS_VOL_OFF 32768

// Early-termination threshold. T ~ e^{-0.107 n} on this data, so 1e-4 stops
// at n~86 vs 1e-6 at n~130 (-34% iterations on long rays). Truncation error:
// depth <= T*(~20) = 2e-3 raw -> ~1e-3 normalized; opacity <= 1e-4. Both far
// below the 2e-2 threshold.
#define T_BREAK 1e-4f

__device__ __forceinline__ float lerpf(float a, float b, float f) {
    return fmaf(f, b - a, a);
}

__global__ __launch_bounds__(256)
void pack_kernel(const float* __restrict__ vox, float* __restrict__ pv) {
    const int idx = blockIdx.x * 256 + threadIdx.x;
    if (idx >= PVOX_ELEMS) return;
    const int zp = idx / SS;
    const int rem = idx - zp * SS;
    const int yp = rem / XS;
    const int xp = rem - yp * XS;
    const int x = xp - 1, y = yp - 1, zz = zp - 1;
    float v = 0.0f;
    if (((unsigned)x < 256u) & ((unsigned)y < 256u)) {
        if (zz == 0) v = 1000.0f;
        else if ((unsigned)(zz - 1) < 64u) v = vox[((zz - 1) << 16) + (y << 8) + x];
    }
    pv[idx] = v;
}

__device__ __forceinline__ float sample_sigma(const float* __restrict__ pvv,
                                              float fs, float sxd, float syd, float szd) {
    const float xf = fmaf(fs, sxd, 127.5f);
    const float yf = fmaf(fs, syd, 127.5f);
    const float zf = fmaf(fs, szd, 1.53125f);
    const float xw = floorf(xf), yw = floorf(yf), zw = floorf(zf);
    const float fx = xf - xw, fy = yf - yw, fz = zf - zw;
    const int x0 = (int)xw, y0 = (int)yw, z0 = (int)zw;
    const int off = z0 * SS + y0 * XS + x0 + (SS + XS + 1);   // +1 pad shift each axis
    const float* p = pvv + off;
    const float c000 = p[0];
    const float c001 = p[1];
    const float c010 = p[XS];
    const float c011 = p[XS + 1];
    const float c100 = p[SS];
    const float c101 = p[SS + 1];
    const float c110 = p[SS + XS];
    const float c111 = p[SS + XS + 1];
    const float l00 = lerpf(c000, c001, fx);
    const float l01 = lerpf(c010, c011, fx);
    const float l10 = lerpf(c100, c101, fx);
    const float l11 = lerpf(c110, c111, fx);
    return lerpf(lerpf(l00, l01, fy), lerpf(l10, l11, fy), fz);
}

__global__ __launch_bounds__(64)
void render_kernel(const float* __restrict__ pvv,
                   float* __restrict__ out,
                   float* __restrict__ bmin, float* __restrict__ bmax) {
    const int lane = threadIdx.x;
    const int r = blockIdx.x * 64 + lane;
    const int h = r >> 9;
    const int w = r & (PW - 1);

    const float lat = (0.5f - (float)h * (1.0f / 255.0f)) * PI_F;
    const float lon = (-0.5f - 2.0f * (float)w * (1.0f / 511.0f)) * PI_F;
    float cl, sl, clon, slon;
    __sincosf(lat, &sl, &cl);
    __sincosf(lon, &slon, &clon);
    const float sxd = cl * clon * (128.0f / NS);
    const float syd = -cl * slon * (128.0f / NS);
    const float szd = sl * (65.0f / NS);
    const float intv = 64.0f / (float)NS;

    // Ray-box clip: samples with pos outside box have exactly sigma=0 (pads),
    // and the box is convex so once out, always out. Samples s=1..nrun valid.
    const float m = 1e-3f;
    float nx = 1e9f, ny = 1e9f, nz = 1e9f;
    if (sxd >  1e-8f) nx = (256.0f - m - 127.5f) / sxd;
    if (sxd < -1e-8f) nx = (127.5f - (-1.0f + m)) / (-sxd);
    if (syd >  1e-8f) ny = (256.0f - m - 127.5f) / syd;
    if (syd < -1e-8f) ny = (127.5f - (-1.0f + m)) / (-syd);
    if (szd >  1e-8f) nz = (65.0f - m - 1.53125f) / szd;
    if (szd < -1e-8f) nz = (1.53125f - (-1.0f + m)) / (-szd);
    const float nmin = fminf(fminf(nx, ny), nz);
    int nrun = NS;
    if (nmin < (float)NS) nrun = (int)nmin;
    if (nrun < 0) nrun = 0;

    float T = 1.0f, depth = 0.0f, opac = 0.0f, dval = 0.0f;

    int i = 0;
    for (; i + 4 <= nrun; i += 4) {
        float sg[4];
        const float fb = (float)i;
        #pragma unroll
        for (int j = 0; j < 4; ++j)
            sg[j] = sample_sigma(pvv, fb + (float)(j + 1), sxd, syd, szd);
        #pragma unroll
        for (int j = 0; j < 4; ++j) {
            const float e = __expf(-sg[j] * intv);
            const float prob = fmaf(-T, e, T);     // T*(1-e)
            dval += intv;
            depth = fmaf(prob, dval, depth);
            opac += prob;
            T *= e;
        }
        if (T < T_BREAK) break;
    }
    if (T >= T_BREAK) {
        for (; i < nrun; ++i) {
            const float sg = sample_sigma(pvv, (float)(i + 1), sxd, syd, szd);
            const float e = __expf(-sg * intv);
            const float prob = fmaf(-T, e, T);
            dval += intv;
            depth = fmaf(prob, dval, depth);
            opac += prob;
            T *= e;
            if (T < T_BREAK) break;
        }
    }

    out[r] = depth;
    out[NRAYS + r] = opac;

    // wave min/max of depth
    float mn = depth, mx = depth;
    #pragma unroll
    for (int off = 32; off > 0; off >>= 1) {
        mn = fminf(mn, __shfl_xor(mn, off));
        mx = fmaxf(mx, __shfl_xor(mx, off));
    }
    if (lane == 0) {
        bmin[blockIdx.x] = mn;
        bmax[blockIdx.x] = mx;
    }
}

__global__ __launch_bounds__(256)
void reduce_minmax_kernel(const float* __restrict__ blockMin,
                          const float* __restrict__ blockMax,
                          float* __restrict__ mm) {
    __shared__ float smn[256];
    __shared__ float smx[256];
    const int t = threadIdx.x;
    float mn = 1e30f, mx = -1e30f;
    for (int i = t; i < NB64; i += 256) {
        mn = fminf(mn, blockMin[i]);
        mx = fmaxf(mx, blockMax[i]);
    }
    smn[t] = mn;
    smx[t] = mx;
    __syncthreads();
    #pragma unroll
    for (int sft = 128; sft > 0; sft >>= 1) {
        if (t < sft) {
            smn[t] = fminf(smn[t], smn[t + sft]);
            smx[t] = fmaxf(smx[t], smx[t + sft]);
        }
        __syncthreads();
    }
    if (t == 0) {
        mm[0] = smn[0];
        mm[1] = smx[0];
    }
}

__global__ __launch_bounds__(256)
void normalize_kernel(float* __restrict__ out, const float* __restrict__ mm) {
    const int r = blockIdx.x * 256 + threadIdx.x;
    const float mn = mm[0];
    const float mx = mm[1];
    out[r] = (out[r] - mn) / (mx - mn);
}

extern "C" void kernel_launch(void* const* d_in, const int* in_sizes, int n_in,
                              void* d_out, int out_size, void* d_ws, size_t ws_size,
                              hipStream_t stream) {
    const float* vox = (const float*)d_in[0];
    float* out = (float*)d_out;
    char* ws = (char*)d_ws;
    float* bmin = (float*)ws;               // 2048 floats
    float* bmax = (float*)(ws + 8192);      // 2048 floats
    float* mm   = (float*)(ws + 16384);     // 2 floats
    float* pv = (float*)(ws + WS_VOL_OFF);

    const int pblocks = (PVOX_ELEMS + 255) / 256;
    pack_kernel<<<pblocks, 256, 0, stream>>>(vox, pv);
    render_kernel<<<NB64, 64, 0, stream>>>(pv, out, bmin, bmax);
    reduce_minmax_kernel<<<1, 256, 0, stream>>>(bmin, bmax, mm);
    normalize_kernel<<<NRAYS / 256, 256, 0, stream>>>(out, mm);
}

// Round 13
// 33.263 us; speedup vs baseline: 1.7864x; 1.2354x over previous
//
#include <hip/hip_runtime.h>
#include <math.h>

// Problem constants (match reference)
#define PH 256
#define PW 512
#define NRAYS (PH * PW)     // 131072
#define NS 300
#define NB64 (NRAYS / 64)   // 2048 one-wave blocks
#define PI_F 3.14159265358979323846f

// Padded f32 volume: P[zp][yp][xp], zp in [0,66], yp/xp in [0,257].
// Logical (zz,y,x) = (zp-1, yp-1, xp-1); zz=0 -> ground 1000, zz in [1,64] ->
// voxel[zz-1], everything else (pads) = 0. Zero padding == reference's
// out-of-range gather = 0, so the render loop needs NO bounds logic at all.
#define XS 258
#define SS (258 * 258)          // 66564
#define ZSL 67
#define PVOX_ELEMS (ZSL * SS)   // 4,459,788
#define WS_VOL_OFF 32768

// Early-termination threshold. T ~ e^{-0.107 n} on this data: 1e-3 stops at
// n~65 vs 1e-4 at n~86 (-25% iterations on long rays). Truncation error:
// missing depth <= T*(d_n + ~2) ~ 0.016 raw -> ~4e-3 normalized, correlated
// across rays (partially cancels via min/max). Threshold is 2e-2.
#define T_BREAK 1e-3f

__device__ __forceinline__ float lerpf(float a, float b, float f) {
    return fmaf(f, b - a, a);
}

__global__ __launch_bounds__(256)
void pack_kernel(const float* __restrict__ vox, float* __restrict__ pv) {
    const int idx = blockIdx.x * 256 + threadIdx.x;
    if (idx >= PVOX_ELEMS) return;
    const int zp = idx / SS;
    const int rem = idx - zp * SS;
    const int yp = rem / XS;
    const int xp = rem - yp * XS;
    const int x = xp - 1, y = yp - 1, zz = zp - 1;
    float v = 0.0f;
    if (((unsigned)x < 256u) & ((unsigned)y < 256u)) {
        if (zz == 0) v = 1000.0f;
        else if ((unsigned)(zz - 1) < 64u) v = vox[((zz - 1) << 16) + (y << 8) + x];
    }
    pv[idx] = v;
}

__device__ __forceinline__ float sample_sigma(const float* __restrict__ pvv,
                                              float fs, float sxd, float syd, float szd) {
    const float xf = fmaf(fs, sxd, 127.5f);
    const float yf = fmaf(fs, syd, 127.5f);
    const float zf = fmaf(fs, szd, 1.53125f);
    const float xw = floorf(xf), yw = floorf(yf), zw = floorf(zf);
    const float fx = xf - xw, fy = yf - yw, fz = zf - zw;
    const int x0 = (int)xw, y0 = (int)yw, z0 = (int)zw;
    const int off = z0 * SS + y0 * XS + x0 + (SS + XS + 1);   // +1 pad shift each axis
    const float* p = pvv + off;
    const float c000 = p[0];
    const float c001 = p[1];
    const float c010 = p[XS];
    const float c011 = p[XS + 1];
    const float c100 = p[SS];
    const float c101 = p[SS + 1];
    const float c110 = p[SS + XS];
    const float c111 = p[SS + XS + 1];
    const float l00 = lerpf(c000, c001, fx);
    const float l01 = lerpf(c010, c011, fx);
    const float l10 = lerpf(c100, c101, fx);
    const float l11 = lerpf(c110, c111, fx);
    return lerpf(lerpf(l00, l01, fy), lerpf(l10, l11, fy), fz);
}

__global__ __launch_bounds__(64)
void render_kernel(const float* __restrict__ pvv,
                   float* __restrict__ out,
                   float* __restrict__ bmin, float* __restrict__ bmax) {
    const int lane = threadIdx.x;
    const int r = blockIdx.x * 64 + lane;
    const int h = r >> 9;
    const int w = r & (PW - 1);

    const float lat = (0.5f - (float)h * (1.0f / 255.0f)) * PI_F;
    const float lon = (-0.5f - 2.0f * (float)w * (1.0f / 511.0f)) * PI_F;
    float cl, sl, clon, slon;
    __sincosf(lat, &sl, &cl);
    __sincosf(lon, &slon, &clon);
    const float sxd = cl * clon * (128.0f / NS);
    const float syd = -cl * slon * (128.0f / NS);
    const float szd = sl * (65.0f / NS);
    const float intv = 64.0f / (float)NS;

    // Ray-box clip: samples with pos outside box have exactly sigma=0 (pads),
    // and the box is convex so once out, always out. Samples s=1..nrun valid.
    const float m = 1e-3f;
    float nx = 1e9f, ny = 1e9f, nz = 1e9f;
    if (sxd >  1e-8f) nx = (256.0f - m - 127.5f) / sxd;
    if (sxd < -1e-8f) nx = (127.5f - (-1.0f + m)) / (-sxd);
    if (syd >  1e-8f) ny = (256.0f - m - 127.5f) / syd;
    if (syd < -1e-8f) ny = (127.5f - (-1.0f + m)) / (-syd);
    if (szd >  1e-8f) nz = (65.0f - m - 1.53125f) / szd;
    if (szd < -1e-8f) nz = (1.53125f - (-1.0f + m)) / (-szd);
    const float nmin = fminf(fminf(nx, ny), nz);
    int nrun = NS;
    if (nmin < (float)NS) nrun = (int)nmin;
    if (nrun < 0) nrun = 0;

    float T = 1.0f, depth = 0.0f, opac = 0.0f, dval = 0.0f;

    int i = 0;
    for (; i + 4 <= nrun; i += 4) {
        float sg[4];
        const float fb = (float)i;
        #pragma unroll
        for (int j = 0; j < 4; ++j)
            sg[j] = sample_sigma(pvv, fb + (float)(j + 1), sxd, syd, szd);
        #pragma unroll
        for (int j = 0; j < 4; ++j) {
            const float e = __expf(-sg[j] * intv);
            const float prob = fmaf(-T, e, T);     // T*(1-e)
            dval += intv;
            depth = fmaf(prob, dval, depth);
            opac += prob;
            T *= e;
        }
        if (T < T_BREAK) break;
    }
    if (T >= T_BREAK) {
        for (; i < nrun; ++i) {
            const float sg = sample_sigma(pvv, (float)(i + 1), sxd, syd, szd);
            const float e = __expf(-sg * intv);
            const float prob = fmaf(-T, e, T);
            dval += intv;
            depth = fmaf(prob, dval, depth);
            opac += prob;
            T *= e;
            if (T < T_BREAK) break;
        }
    }

    out[r] = depth;
    out[NRAYS + r] = opac;

    // wave min/max of depth
    float mn = depth, mx = depth;
    #pragma unroll
    for (int off = 32; off > 0; off >>= 1) {
        mn = fminf(mn, __shfl_xor(mn, off));
        mx = fmaxf(mx, __shfl_xor(mx, off));
    }
    if (lane == 0) {
        bmin[blockIdx.x] = mn;
        bmax[blockIdx.x] = mx;
    }
}

// Fused: every block redundantly reduces the 2048-entry bmin/bmax arrays
// (16 KB, L2-hot, ~free) then normalizes its 256-ray slice of depth.
// Removes the separate 1-block reduce kernel + one launch gap.
__global__ __launch_bounds__(256)
void normalize_fused_kernel(float* __restrict__ out,
                            const float* __restrict__ blockMin,
                            const float* __restrict__ blockMax) {
    const int t = threadIdx.x;
    float mn = 1e30f, mx = -1e30f;
    #pragma unroll
    for (int k = 0; k < NB64 / 256; ++k) {
        mn = fminf(mn, blockMin[k * 256 + t]);
        mx = fmaxf(mx, blockMax[k * 256 + t]);
    }
    // wave reduce
    #pragma unroll
    for (int off = 32; off > 0; off >>= 1) {
        mn = fminf(mn, __shfl_xor(mn, off));
        mx = fmaxf(mx, __shfl_xor(mx, off));
    }
    // cross-wave via LDS (4 waves)
    __shared__ float smn[4], smx[4];
    if ((t & 63) == 0) {
        smn[t >> 6] = mn;
        smx[t >> 6] = mx;
    }
    __syncthreads();
    mn = fminf(fminf(smn[0], smn[1]), fminf(smn[2], smn[3]));
    mx = fmaxf(fmaxf(smx[0], smx[1]), fmaxf(smx[2], smx[3]));

    const int r = blockIdx.x * 256 + t;
    out[r] = (out[r] - mn) / (mx - mn);
}

extern "C" void kernel_launch(void* const* d_in, const int* in_sizes, int n_in,
                              void* d_out, int out_size, void* d_ws, size_t ws_size,
                              hipStream_t stream) {
    const float* vox = (const float*)d_in[0];
    float* out = (float*)d_out;
    char* ws = (char*)d_ws;
    float* bmin = (float*)ws;               // 2048 floats
    float* bmax = (float*)(ws + 8192);      // 2048 floats
    float* pv = (float*)(ws + WS_VOL_OFF);

    const int pblocks = (PVOX_ELEMS + 255) / 256;
    pack_kernel<<<pblocks, 256, 0, stream>>>(vox, pv);
    render_kernel<<<NB64, 64, 0, stream>>>(pv, out, bmin, bmax);
    normalize_fused_kernel<<<NRAYS / 256, 256, 0, stream>>>(out, bmin, bmax);
}

// Round 14
// 32.965 us; speedup vs baseline: 1.8026x; 1.0090x over previous
//
#include <hip/hip_runtime.h>
#include <math.h>

// Problem constants (match reference)
#define PH 256
#define PW 512
#define NRAYS (PH * PW)     // 131072
#define NS 300
#define NB64 (NRAYS / 64)   // 2048 one-wave blocks
#define PI_F 3.14159265358979323846f

// Early-termination threshold (see r12/r13 analysis): T ~ e^{-0.107 n} on
// this data; 1e-3 stops at n~65. absmax measured 0.0078 vs threshold 2e-2.
#define T_BREAK 1e-3f

// No packed volume: render reads the original voxel (64 slices of 256x256)
// directly. Geometry proof (|sxd|,|syd| <= 0.427, |szd| <= 0.217 per step,
// T-break at n<~80): rays terminate long before any outer boundary (x/y exit
// needs n~300, z-top n~288). The only boundary case is the ground slab
// (cell z0 == 0): node 0 is the constant-1000 ground plane, node 1 is voxel
// slice 0 -> handled with 4 cndmasks. Tight clip guarantees indices in range
// even for the 4-wide batches.

__device__ __forceinline__ float lerpf(float a, float b, float f) {
    return fmaf(f, b - a, a);
}

// z-continuous coords: node k at zc = k; node 0 = ground(1000), node k>=1 =
// voxel slice k-1. Camera at zc0 = 1.53125. Cell z0 = floor(zc) in [0,63]:
// low corners from voxel slice z0-1 (ground const if z0==0), high corners
// from voxel slice z0.
__device__ __forceinline__ float sample_sigma(const float* __restrict__ vox,
                                              float fs, float sxd, float syd, float szd) {
    const float xf = fmaf(fs, sxd, 127.5f);
    const float yf = fmaf(fs, syd, 127.5f);
    const float zf = fmaf(fs, szd, 1.53125f);
    const float xw = floorf(xf), yw = floorf(yf), zw = floorf(zf);
    const float fx = xf - xw, fy = yf - yw, fz = zf - zw;
    const int x0 = (int)xw, y0 = (int)yw, z0 = (int)zw;

    const int zlo = (z0 > 0) ? (z0 - 1) : 0;
    const bool gnd = (z0 == 0);
    const int xy = (y0 << 8) + x0;
    const float* pLo = vox + ((zlo << 16) + xy);
    const float* pHi = vox + ((z0 << 16) + xy);

    const float c000 = gnd ? 1000.0f : pLo[0];
    const float c001 = gnd ? 1000.0f : pLo[1];
    const float c010 = gnd ? 1000.0f : pLo[256];
    const float c011 = gnd ? 1000.0f : pLo[257];
    const float c100 = pHi[0];
    const float c101 = pHi[1];
    const float c110 = pHi[256];
    const float c111 = pHi[257];

    const float l00 = lerpf(c000, c001, fx);
    const float l01 = lerpf(c010, c011, fx);
    const float l10 = lerpf(c100, c101, fx);
    const float l11 = lerpf(c110, c111, fx);
    return lerpf(lerpf(l00, l01, fy), lerpf(l10, l11, fy), fz);
}

__global__ __launch_bounds__(64)
void render_kernel(const float* __restrict__ vox,
                   float* __restrict__ out,
                   float* __restrict__ bmin, float* __restrict__ bmax) {
    const int lane = threadIdx.x;
    const int r = blockIdx.x * 64 + lane;
    const int h = r >> 9;
    const int w = r & (PW - 1);

    const float lat = (0.5f - (float)h * (1.0f / 255.0f)) * PI_F;
    const float lon = (-0.5f - 2.0f * (float)w * (1.0f / 511.0f)) * PI_F;
    float cl, sl, clon, slon;
    __sincosf(lat, &sl, &cl);
    __sincosf(lon, &slon, &clon);
    const float sxd = cl * clon * (128.0f / NS);
    const float syd = -cl * slon * (128.0f / NS);
    const float szd = sl * (65.0f / NS);
    const float intv = 64.0f / (float)NS;

    // Tight ray-box clip: keep xf,yf in [m, 255-m], zf in [m, 64-m] so every
    // marched sample has x0,y0 in [0,254] and z0 in [0,63] (no OOB possible).
    // Everything clipped away is provably dead (T=0 below ground; sigma=0 /
    // negligible beyond walls; T-break fires first on this data anyway).
    const float m = 1e-3f;
    float nx = 1e9f, ny = 1e9f, nz = 1e9f;
    if (sxd >  1e-8f) nx = (255.0f - m - 127.5f) / sxd;
    if (sxd < -1e-8f) nx = (127.5f - m) / (-sxd);
    if (syd >  1e-8f) ny = (255.0f - m - 127.5f) / syd;
    if (syd < -1e-8f) ny = (127.5f - m) / (-syd);
    if (szd >  1e-8f) nz = (64.0f - m - 1.53125f) / szd;
    if (szd < -1e-8f) nz = (1.53125f - m) / (-szd);
    const float nmin = fminf(fminf(nx, ny), nz);
    int nrun = NS;
    if (nmin < (float)NS) nrun = (int)nmin;
    if (nrun < 0) nrun = 0;

    float T = 1.0f, depth = 0.0f, opac = 0.0f, dval = 0.0f;

    int i = 0;
    for (; i + 4 <= nrun; i += 4) {
        float sg[4];
        const float fb = (float)i;
        #pragma unroll
        for (int j = 0; j < 4; ++j)
            sg[j] = sample_sigma(vox, fb + (float)(j + 1), sxd, syd, szd);
        #pragma unroll
        for (int j = 0; j < 4; ++j) {
            const float e = __expf(-sg[j] * intv);
            const float prob = fmaf(-T, e, T);     // T*(1-e)
            dval += intv;
            depth = fmaf(prob, dval, depth);
            opac += prob;
            T *= e;
        }
        if (T < T_BREAK) break;
    }
    if (T >= T_BREAK) {
        for (; i < nrun; ++i) {
            const float sg = sample_sigma(vox, (float)(i + 1), sxd, syd, szd);
            const float e = __expf(-sg * intv);
            const float prob = fmaf(-T, e, T);
            dval += intv;
            depth = fmaf(prob, dval, depth);
            opac += prob;
            T *= e;
            if (T < T_BREAK) break;
        }
    }

    out[r] = depth;
    out[NRAYS + r] = opac;

    // wave min/max of depth
    float mn = depth, mx = depth;
    #pragma unroll
    for (int off = 32; off > 0; off >>= 1) {
        mn = fminf(mn, __shfl_xor(mn, off));
        mx = fmaxf(mx, __shfl_xor(mx, off));
    }
    if (lane == 0) {
        bmin[blockIdx.x] = mn;
        bmax[blockIdx.x] = mx;
    }
}

// Fused: every block redundantly reduces the 2048-entry bmin/bmax arrays
// (16 KB, L2-hot, ~free) then normalizes its 256-ray slice of depth.
__global__ __launch_bounds__(256)
void normalize_fused_kernel(float* __restrict__ out,
                            const float* __restrict__ blockMin,
                            const float* __restrict__ blockMax) {
    const int t = threadIdx.x;
    float mn = 1e30f, mx = -1e30f;
    #pragma unroll
    for (int k = 0; k < NB64 / 256; ++k) {
        mn = fminf(mn, blockMin[k * 256 + t]);
        mx = fmaxf(mx, blockMax[k * 256 + t]);
    }
    // wave reduce
    #pragma unroll
    for (int off = 32; off > 0; off >>= 1) {
        mn = fminf(mn, __shfl_xor(mn, off));
        mx = fmaxf(mx, __shfl_xor(mx, off));
    }
    // cross-wave via LDS (4 waves)
    __shared__ float smn[4], smx[4];
    if ((t & 63) == 0) {
        smn[t >> 6] = mn;
        smx[t >> 6] = mx;
    }
    __syncthreads();
    mn = fminf(fminf(smn[0], smn[1]), fminf(smn[2], smn[3]));
    mx = fmaxf(fmaxf(smx[0], smx[1]), fmaxf(smx[2], smx[3]));

    const int r = blockIdx.x * 256 + t;
    out[r] = (out[r] - mn) / (mx - mn);
}

extern "C" void kernel_launch(void* const* d_in, const int* in_sizes, int n_in,
                              void* d_out, int out_size, void* d_ws, size_t ws_size,
                              hipStream_t stream) {
    const float* vox = (const float*)d_in[0];
    float* out = (float*)d_out;
    char* ws = (char*)d_ws;
    float* bmin = (float*)ws;               // 2048 floats
    float* bmax = (float*)(ws + 8192);      // 2048 floats

    render_kernel<<<NB64, 64, 0, stream>>>(vox, out, bmin, bmax);
    normalize_fused_kernel<<<NRAYS / 256, 256, 0, stream>>>(out, bmin, bmax);
}

// Round 15
// 24.512 us; speedup vs baseline: 2.4242x; 1.3449x over previous
//
#include <hip/hip_runtime.h>
#include <math.h>

// Problem constants (match reference)
#define PH 256
#define PW 512
#define NRAYS (PH * PW)     // 131072
#define NS 300
#define NB64 (NRAYS / 64)   // 2048 one-wave blocks
#define PI_F 3.14159265358979323846f

// Early-termination threshold (r12/r13 analysis): T ~ e^{-0.107 n} on this
// data; 1e-3 stops at n~65. absmax measured 0.0078 vs threshold 2e-2.
#define T_BREAK 1e-3f

// Render reads the original voxel (64 slices of 256x256) directly.
// Ground slab (cell z0==0): node 0 = constant 1000, node 1 = voxel slice 0
// -> 4 cndmasks at consume time. Tight ray-box clip keeps x0,y0 in [0,254],
// z0 in [0,63] for every marched (and prefetch-clamped) sample.

__device__ __forceinline__ float lerpf(float a, float b, float f) {
    return fmaf(f, b - a, a);
}

// One in-flight sample: 8 corners + fractions + ground flag. Two named
// 4-sample register sets (A/B) are ping-ponged by a manually 2-unrolled
// loop so all indexing is compile-time (no scratch).
struct Smp {
    float c0, c1, c2, c3, c4, c5, c6, c7;
    float fx, fy, fz;
    bool g;
};

// Issue the 32 corner loads for 4 samples starting at fsbase+1 (clamped to
// fnrun so speculative prefetch batches stay inside the clip box).
#define LOADS(S, fsbase)                                                   \
    _Pragma("unroll")                                                      \
    for (int j = 0; j < 4; ++j) {                                          \
        const float fs = fminf((fsbase) + (float)(j + 1), fnrun);          \
        const float xf = fmaf(fs, sxd, 127.5f);                            \
        const float yf = fmaf(fs, syd, 127.5f);                            \
        const float zf = fmaf(fs, szd, 1.53125f);                          \
        const float xw = floorf(xf), yw = floorf(yf), zw = floorf(zf);     \
        S[j].fx = xf - xw; S[j].fy = yf - yw; S[j].fz = zf - zw;           \
        const int x0 = (int)xw, y0 = (int)yw, z0 = (int)zw;                \
        const int zlo = (z0 > 0) ? (z0 - 1) : 0;                           \
        S[j].g = (z0 == 0);                                                \
        const int xy = (y0 << 8) + x0;                                     \
        const float* pLo = vox + ((zlo << 16) + xy);                       \
        const float* pHi = vox + ((z0 << 16) + xy);                        \
        S[j].c0 = pLo[0];   S[j].c1 = pLo[1];                              \
        S[j].c2 = pLo[256]; S[j].c3 = pLo[257];                            \
        S[j].c4 = pHi[0];   S[j].c5 = pHi[1];                              \
        S[j].c6 = pHi[256]; S[j].c7 = pHi[257];                            \
    }

// Consume 4 samples: ground select, 7 lerps, exp, transmittance accumulate.
#define CONS(S)                                                            \
    _Pragma("unroll")                                                      \
    for (int j = 0; j < 4; ++j) {                                          \
        const float d000 = S[j].g ? 1000.0f : S[j].c0;                     \
        const float d001 = S[j].g ? 1000.0f : S[j].c1;                     \
        const float d010 = S[j].g ? 1000.0f : S[j].c2;                     \
        const float d011 = S[j].g ? 1000.0f : S[j].c3;                     \
        const float l00 = lerpf(d000, d001, S[j].fx);                      \
        const float l01 = lerpf(d010, d011, S[j].fx);                      \
        const float l10 = lerpf(S[j].c4, S[j].c5, S[j].fx);                \
        const float l11 = lerpf(S[j].c6, S[j].c7, S[j].fx);                \
        const float sg = lerpf(lerpf(l00, l01, S[j].fy),                   \
                               lerpf(l10, l11, S[j].fy), S[j].fz);         \
        const float e = __expf(-sg * intv);                                \
        const float prob = fmaf(-T, e, T);                                 \
        dval += intv;                                                      \
        depth = fmaf(prob, dval, depth);                                   \
        opac += prob;                                                      \
        T *= e;                                                            \
    }

__device__ __forceinline__ float sample_sigma(const float* __restrict__ vox,
                                              float fs, float sxd, float syd, float szd) {
    const float xf = fmaf(fs, sxd, 127.5f);
    const float yf = fmaf(fs, syd, 127.5f);
    const float zf = fmaf(fs, szd, 1.53125f);
    const float xw = floorf(xf), yw = floorf(yf), zw = floorf(zf);
    const float fx = xf - xw, fy = yf - yw, fz = zf - zw;
    const int x0 = (int)xw, y0 = (int)yw, z0 = (int)zw;
    const int zlo = (z0 > 0) ? (z0 - 1) : 0;
    const bool gnd = (z0 == 0);
    const int xy = (y0 << 8) + x0;
    const float* pLo = vox + ((zlo << 16) + xy);
    const float* pHi = vox + ((z0 << 16) + xy);
    const float c000 = gnd ? 1000.0f : pLo[0];
    const float c001 = gnd ? 1000.0f : pLo[1];
    const float c010 = gnd ? 1000.0f : pLo[256];
    const float c011 = gnd ? 1000.0f : pLo[257];
    const float c100 = pHi[0];
    const float c101 = pHi[1];
    const float c110 = pHi[256];
    const float c111 = pHi[257];
    const float l00 = lerpf(c000, c001, fx);
    const float l01 = lerpf(c010, c011, fx);
    const float l10 = lerpf(c100, c101, fx);
    const float l11 = lerpf(c110, c111, fx);
    return lerpf(lerpf(l00, l01, fy), lerpf(l10, l11, fy), fz);
}

__global__ __launch_bounds__(64)
void render_kernel(const float* __restrict__ vox,
                   float* __restrict__ out,
                   float* __restrict__ bmin, float* __restrict__ bmax) {
    const int lane = threadIdx.x;
    const int r = blockIdx.x * 64 + lane;
    const int h = r >> 9;
    const int w = r & (PW - 1);

    const float lat = (0.5f - (float)h * (1.0f / 255.0f)) * PI_F;
    const float lon = (-0.5f - 2.0f * (float)w * (1.0f / 511.0f)) * PI_F;
    float cl, sl, clon, slon;
    __sincosf(lat, &sl, &cl);
    __sincosf(lon, &slon, &clon);
    const float sxd = cl * clon * (128.0f / NS);
    const float syd = -cl * slon * (128.0f / NS);
    const float szd = sl * (65.0f / NS);
    const float intv = 64.0f / (float)NS;

    // Tight ray-box clip: xf,yf in [m,255-m], zf in [m,64-m] -> x0,y0 in
    // [0,254], z0 in [0,63] for all marched samples. Clipped region is
    // provably dead (T=0 below ground / sigma=0 or T-break fires first).
    const float m = 1e-3f;
    float nx = 1e9f, ny = 1e9f, nz = 1e9f;
    if (sxd >  1e-8f) nx = (255.0f - m - 127.5f) / sxd;
    if (sxd < -1e-8f) nx = (127.5f - m) / (-sxd);
    if (syd >  1e-8f) ny = (255.0f - m - 127.5f) / syd;
    if (syd < -1e-8f) ny = (127.5f - m) / (-syd);
    if (szd >  1e-8f) nz = (64.0f - m - 1.53125f) / szd;
    if (szd < -1e-8f) nz = (1.53125f - m) / (-szd);
    const float nmin = fminf(fminf(nx, ny), nz);
    int nrun = NS;
    if (nmin < (float)NS) nrun = (int)nmin;
    if (nrun < 0) nrun = 0;
    const float fnrun = (float)nrun;

    float T = 1.0f, depth = 0.0f, opac = 0.0f, dval = 0.0f;

    int i = 0;
    // Software-pipelined main loop: batch i+4's 32 loads are issued before
    // batch i is consumed, so consume math (~400 cyc) hides load latency.
    if (nrun >= 4) {
        Smp A[4], B[4];
        LOADS(A, 0.0f)
        for (;;) {
            LOADS(B, (float)(i + 4))     // prefetch (clamped; maybe discarded)
            CONS(A)                      // waits only on A's loads
            i += 4;
            if ((T < T_BREAK) | (i + 4 > nrun)) break;
            LOADS(A, (float)(i + 4))
            CONS(B)
            i += 4;
            if ((T < T_BREAK) | (i + 4 > nrun)) break;
        }
    }
    // scalar tail
    if (T >= T_BREAK) {
        for (; i < nrun; ++i) {
            const float sg = sample_sigma(vox, (float)(i + 1), sxd, syd, szd);
            const float e = __expf(-sg * intv);
            const float prob = fmaf(-T, e, T);
            dval += intv;
            depth = fmaf(prob, dval, depth);
            opac += prob;
            T *= e;
            if (T < T_BREAK) break;
        }
    }

    out[r] = depth;
    out[NRAYS + r] = opac;

    // wave min/max of depth
    float mn = depth, mx = depth;
    #pragma unroll
    for (int off = 32; off > 0; off >>= 1) {
        mn = fminf(mn, __shfl_xor(mn, off));
        mx = fmaxf(mx, __shfl_xor(mx, off));
    }
    if (lane == 0) {
        bmin[blockIdx.x] = mn;
        bmax[blockIdx.x] = mx;
    }
}

// Fused: every block redundantly reduces the 2048-entry bmin/bmax arrays
// (16 KB, L2-hot, ~free) then normalizes its 256-ray slice of depth.
__global__ __launch_bounds__(256)
void normalize_fused_kernel(float* __restrict__ out,
                            const float* __restrict__ blockMin,
                            const float* __restrict__ blockMax) {
    const int t = threadIdx.x;
    float mn = 1e30f, mx = -1e30f;
    #pragma unroll
    for (int k = 0; k < NB64 / 256; ++k) {
        mn = fminf(mn, blockMin[k * 256 + t]);
        mx = fmaxf(mx, blockMax[k * 256 + t]);
    }
    #pragma unroll
    for (int off = 32; off > 0; off >>= 1) {
        mn = fminf(mn, __shfl_xor(mn, off));
        mx = fmaxf(mx, __shfl_xor(mx, off));
    }
    __shared__ float smn[4], smx[4];
    if ((t & 63) == 0) {
        smn[t >> 6] = mn;
        smx[t >> 6] = mx;
    }
    __syncthreads();
    mn = fminf(fminf(smn[0], smn[1]), fminf(smn[2], smn[3]));
    mx = fmaxf(fmaxf(smx[0], smx[1]), fmaxf(smx[2], smx[3]));

    const int r = blockIdx.x * 256 + t;
    out[r] = (out[r] - mn) / (mx - mn);
}

extern "C" void kernel_launch(void* const* d_in, const int* in_sizes, int n_in,
                              void* d_out, int out_size, void* d_ws, size_t ws_size,
                              hipStream_t stream) {
    const float* vox = (const float*)d_in[0];
    float* out = (float*)d_out;
    char* ws = (char*)d_ws;
    float* bmin = (float*)ws;               // 2048 floats
    float* bmax = (float*)(ws + 8192);      // 2048 floats

    render_kernel<<<NB64, 64, 0, stream>>>(vox, out, bmin, bmax);
    normalize_fused_kernel<<<NRAYS / 256, 256, 0, stream>>>(out, bmin, bmax);
}